// Round 4
// baseline (512.294 us; speedup 1.0000x reference)
//
#include <hip/hip_runtime.h>
#include <math.h>

// Problem constants
#define B_    8
#define E_    512
#define L_    8192
#define K_    5
#define LC    8188      // L - K + 1
#define LOUT  4096      // L / DS
#define XROWS 8200      // xT t-rows: 8192 data + 8 slack rows (read, never used in valid outputs)
#define LCP   8208      // padded y/z row length: [0,8) front zeros, data at 8+t, back zeros

// Workspace total 137,298,432 B (under round-0 proven 137,592,704 B)

typedef float  f32x4   __attribute__((ext_vector_type(4)));
typedef float  f32x16  __attribute__((ext_vector_type(16)));
typedef short  s16x4   __attribute__((ext_vector_type(4)));
typedef short  s16x8   __attribute__((ext_vector_type(8)));

__device__ __forceinline__ unsigned short f2bf(float f) {
    union { float f; unsigned u; } v; v.f = f;
    unsigned r = v.u + 0x7FFFu + ((v.u >> 16) & 1u);
    return (unsigned short)(r >> 16);
}
__device__ __forceinline__ float bflo(unsigned u) {
    union { unsigned u; float f; } v; v.u = u << 16; return v.f;
}
__device__ __forceinline__ float bfhi(unsigned u) {
    union { unsigned u; float f; } v; v.u = u & 0xFFFF0000u; return v.f;
}

// ---------------------------------------------------------------------------
// Kernel 0: pack conv weight [e][i][k] fp32 -> fragment-ordered Wp, bf16.
// Wp layout: [e0t 8][i0t 16][k 5][kk 2][es 2][lane 64][j 8]
//   e = e0t*64 + es*32 + (lane&31);  i = i0t*32 + kk*16 + (lane>>5)*8 + j
// One MFMA A-fragment = 512 consecutive bf16 (1 KB), lane-major -> conv reads
// it as a single fully-coalesced dwordx4 per lane.
// ---------------------------------------------------------------------------
__global__ __launch_bounds__(256) void wt_kernel(const float* __restrict__ w,
                                                 unsigned short* __restrict__ Wp) {
    int idx = blockIdx.x * 256 + threadIdx.x;
    if (idx >= E_ * E_ * K_) return;
    int j    = idx & 7;
    int lane = (idx >> 3) & 63;
    int es   = (idx >> 9) & 1;
    int kk   = (idx >> 10) & 1;
    int rest = idx >> 11;          // [0, 640)
    int k    = rest % 5;
    int q    = rest / 5;           // [0, 128)
    int i0t  = q & 15;
    int e0t  = q >> 4;
    int e = e0t * 64 + es * 32 + (lane & 31);
    int i = i0t * 32 + kk * 16 + (lane >> 5) * 8 + j;
    Wp[idx] = f2bf(w[((size_t)e * E_ + i) * K_ + k]);
}

// ---------------------------------------------------------------------------
// Kernel 1: transpose x[b][i][t] fp32 -> xT[b][t][i] bf16.
// Phase 1 vectorized to f32x4 (grid covers t exactly, no guard).
// ---------------------------------------------------------------------------
__global__ __launch_bounds__(256) void xt_kernel(const float* __restrict__ x,
                                                 unsigned short* __restrict__ xT) {
    __shared__ float s[64][65];
    const int b  = blockIdx.z;
    const int i0 = blockIdx.y * 64;
    const int t0 = blockIdx.x * 64;
    #pragma unroll
    for (int j = 0; j < 4; ++j) {
        int idx = threadIdx.x + j * 256;
        int r = idx >> 4, c4 = idx & 15;      // r: i-offset, c4: t-chunk of 4
        f32x4 v = *(const f32x4*)(x + ((size_t)b * E_ + i0 + r) * L_ + t0 + c4 * 4);
        s[c4 * 4 + 0][r] = v[0];
        s[c4 * 4 + 1][r] = v[1];
        s[c4 * 4 + 2][r] = v[2];
        s[c4 * 4 + 3][r] = v[3];
    }
    __syncthreads();
    #pragma unroll
    for (int j = 0; j < 4; ++j) {
        int idx = threadIdx.x + j * 256;
        int tt = idx >> 4, ig = (idx & 15) * 4;
        s16x4 v;
        v[0] = (short)f2bf(s[tt][ig + 0]);
        v[1] = (short)f2bf(s[tt][ig + 1]);
        v[2] = (short)f2bf(s[tt][ig + 2]);
        v[3] = (short)f2bf(s[tt][ig + 3]);
        *(s16x4*)&xT[((size_t)b * XROWS + t0 + tt) * E_ + i0 + ig] = v;
    }
}

// ---------------------------------------------------------------------------
// Kernel 2: zero zP[B][LCP] fully (atomic accumulated) + yP edge pads
// ---------------------------------------------------------------------------
__global__ __launch_bounds__(256) void zero_aux(unsigned short* __restrict__ yP,
                                                float* __restrict__ zP) {
    int idx = blockIdx.x * 256 + threadIdx.x;
    if (idx < B_ * LCP) zP[idx] = 0.f;
    int i2 = idx - B_ * LCP;
    if (i2 >= 0 && i2 < B_ * E_ * 20) {
        int row = i2 / 20, j = i2 - row * 20;
        int col = (j < 8) ? j : (8 + LC + (j - 8));   // front 8 + back 12 pads
        yP[(size_t)row * LCP + col] = 0;
    }
}

// ---------------------------------------------------------------------------
// Kernel 3: implicit-GEMM conv via 32x32x16 bf16 MFMA + fused z-score.
// Retiled: block = 64e x 256t, 4 waves, wave = 64e x 64t (acc[2][2], 64 AGPR).
// W read DIRECTLY from fragment-ordered Wp in global (L2-resident, coalesced
// 1KB per fragment) -- no Ws LDS. launch_bounds(256,3): 3 blocks/CU.
// ---------------------------------------------------------------------------
__global__ __launch_bounds__(256, 3) void conv_mfma(const unsigned short* __restrict__ xT,
                                                    const unsigned short* __restrict__ Wp,
                                                    const float* __restrict__ bias,
                                                    const float* __restrict__ sw,
                                                    unsigned short* __restrict__ yP,
                                                    float* __restrict__ zP) {
    __shared__ unsigned short Xs[264][40];   // rows padded to 80 B
    __shared__ float swb[128];               // [0:64) = score_w, [64:128) = bias

    const int tid  = threadIdx.x;
    const int nt   = blockIdx.x;
    const int b    = nt >> 5;
    const int tb   = (nt & 31) * 256;
    const int e0t  = blockIdx.y;
    const int e0   = e0t * 64;
    const int wave = tid >> 6;
    const int lane = tid & 63;
    const int l32  = lane & 31;
    const int hi   = lane >> 5;
    const int wt0  = wave * 64;

    if (tid < 64)       swb[tid] = sw[e0 + tid];
    else if (tid < 128) swb[tid] = bias[e0 + tid - 64];

    f32x16 acc[2][2];
    #pragma unroll
    for (int es = 0; es < 2; ++es)
        #pragma unroll
        for (int ts = 0; ts < 2; ++ts) acc[es][ts] = (f32x16)0.f;

    const unsigned short* xbase = xT + ((size_t)b * XROWS + tb) * E_;
    // per-e0t W block: 16 i0t * 5 k * 2 kk * 2 es * 512 = 163840 ushorts
    const unsigned short* wbase = Wp + (size_t)e0t * 163840 + (size_t)lane * 8;

    // X staging: 264 rows x 4 chunks of 16B = 1056 chunks; 4/thread + 32-thread tail
    s16x8 xpf[5];

    auto load_tile = [&](int i0) {
        #pragma unroll
        for (int j = 0; j < 4; ++j) {
            int idx = tid + j * 256;
            int r = idx >> 2, c = idx & 3;
            xpf[j] = *(const s16x8*)(xbase + (size_t)r * E_ + i0 + c * 8);
        }
        {
            int idx = tid + 1024;
            if (idx < 1056) {
                int r = idx >> 2, c = idx & 3;
                xpf[4] = *(const s16x8*)(xbase + (size_t)r * E_ + i0 + c * 8);
            }
        }
    };
    auto store_tile = [&]() {
        #pragma unroll
        for (int j = 0; j < 4; ++j) {
            int idx = tid + j * 256;
            int r = idx >> 2, c = idx & 3;
            *(s16x8*)&Xs[r][c * 8] = xpf[j];
        }
        {
            int idx = tid + 1024;
            if (idx < 1056) {
                int r = idx >> 2, c = idx & 3;
                *(s16x8*)&Xs[r][c * 8] = xpf[4];
            }
        }
    };

    load_tile(0);
    for (int i0 = 0; i0 < E_; i0 += 32) {
        __syncthreads();            // previous compute done reading LDS
        store_tile();
        __syncthreads();
        if (i0 + 32 < E_) load_tile(i0 + 32);   // latency hidden under MFMAs

        const unsigned short* wfrag = wbase + (size_t)(i0 >> 5) * 10240;
        #pragma unroll
        for (int k = 0; k < K_; ++k) {
            #pragma unroll
            for (int kk = 0; kk < 2; ++kk) {
                // A fragments direct from global (L2): 1KB coalesced each
                s16x8 a0 = *(const s16x8*)(wfrag + (size_t)(((k * 2 + kk) * 2 + 0) * 512));
                s16x8 a1 = *(const s16x8*)(wfrag + (size_t)(((k * 2 + kk) * 2 + 1) * 512));
                const int co = kk * 16 + hi * 8;
                #pragma unroll
                for (int ts = 0; ts < 2; ++ts) {
                    s16x8 bv = *(const s16x8*)&Xs[wt0 + ts * 32 + l32 + k][co];
                    acc[0][ts] = __builtin_amdgcn_mfma_f32_32x32x16_bf16(a0, bv, acc[0][ts], 0, 0, 0);
                    acc[1][ts] = __builtin_amdgcn_mfma_f32_32x32x16_bf16(a1, bv, acc[1][ts], 0, 0, 0);
                }
            }
        }
    }

    // Epilogue: bias add, yP store (bf16, +8 pad offset), fused z partial.
    // C/D layout (32x32): col(t)=lane&31, row(e)=(reg&3)+8*(reg>>2)+4*hi
    #pragma unroll
    for (int ts = 0; ts < 2; ++ts) {
        const int t = tb + wt0 + ts * 32 + l32;
        const bool tv = (t < LC);
        float zp = 0.f;
        #pragma unroll
        for (int es = 0; es < 2; ++es) {
            #pragma unroll
            for (int reg = 0; reg < 16; ++reg) {
                int er = es * 32 + (reg & 3) + 8 * (reg >> 2) + 4 * hi;
                float v = acc[es][ts][reg] + swb[64 + er];
                if (tv) yP[((size_t)(b * E_ + e0 + er)) * LCP + 8 + t] = f2bf(v);
                zp += swb[er] * v;
            }
        }
        zp += __shfl_xor(zp, 32);
        if (hi == 0 && tv) atomicAdd(&zP[(size_t)b * LCP + 8 + t], zp);
    }
}

// ---------------------------------------------------------------------------
// Kernel 4: blend widths 1..3 + 2x downsample (unchanged from round 3).
// ---------------------------------------------------------------------------
__global__ __launch_bounds__(256) void out2_kernel(const unsigned short* __restrict__ yP,
                                                   const float* __restrict__ zP,
                                                   float* __restrict__ out) {
    __shared__ unsigned short ys8[8][1040];   // window [2d0-8, 2d0+1032) in t
    __shared__ float  zsL[1040];
    __shared__ float2 attA[512];              // (W1a, W1b)
    __shared__ float2 attB[512];              // (W2, W3a)
    __shared__ float  attC[512];              // W3b
    const int bx  = blockIdx.x;               // b*64 + eg
    const int b   = bx >> 6;
    const int eg  = bx & 63;
    const int d0  = blockIdx.y << 9;          // * 512
    const int tid = threadIdx.x;

    const unsigned short* ybase = yP + ((size_t)(b * E_ + eg * 8)) * LCP + 2 * d0;
    const float* zbase = zP + (size_t)b * LCP + 2 * d0;

    #pragma unroll
    for (int r = 0; r < 8; ++r) {
        if (tid < 130) {
            s16x8 v = *(const s16x8*)(ybase + (size_t)r * LCP + tid * 8);
            *(s16x8*)&ys8[r][tid * 8] = v;
        }
    }
    for (int c = tid; c < 260; c += 256)
        *(f32x4*)&zsL[c * 4] = *(const f32x4*)(zbase + c * 4);
    __syncthreads();

    for (int dl = tid; dl < 512; dl += 256) {
        int lt = 2 * dl + 6;
        float z0 = zsL[lt + 0], z1 = zsL[lt + 1], z2 = zsL[lt + 2];
        float z3 = zsL[lt + 3], z4 = zsL[lt + 4], z5 = zsL[lt + 5];
        unsigned t  = 2u * (unsigned)(d0 + dl);
        unsigned r3 = t % 3u;
        float a12 = z1 + z2, a34 = z3 + z4;
        float s0 = z0 + a12, s1 = a12 + z3, s2 = z2 + a34, s3 = a34 + z5;
        float S1a = z2, S1b = z3;
        float S2  = 0.5f * (z2 + z3);
        float S3a = ((r3 == 0u) ? s2 : ((r3 == 1u) ? s1 : s0)) * (1.f / 3.f);
        float S3b = ((r3 == 0u) ? s2 : ((r3 == 1u) ? s1 : s3)) * (1.f / 3.f);
        float m0 = fmaxf(S1a, fmaxf(S2, S3a));
        float e1 = __expf(S1a - m0), e2 = __expf(S2 - m0), e3 = __expf(S3a - m0);
        float r0 = 1.f / (e1 + e2 + e3);
        float m1 = fmaxf(S1b, fmaxf(S2, S3b));
        float f1 = __expf(S1b - m1), f2 = __expf(S2 - m1), f3 = __expf(S3b - m1);
        float r1 = 1.f / (f1 + f2 + f3);
        attA[dl] = make_float2(0.5f * e1 * r0, 0.5f * f1 * r1);
        attB[dl] = make_float2(0.25f * (e2 * r0 + f2 * r1), (0.5f / 3.f) * e3 * r0);
        attC[dl] = (0.5f / 3.f) * f3 * r1;
    }
    __syncthreads();

    const int e    = tid >> 5;
    const int l32b = tid & 31;
    float* orow = out + ((size_t)(b * E_ + eg * 8 + e)) * LOUT + d0;
    const unsigned short* yr = &ys8[e][0];
    #pragma unroll
    for (int ii = 0; ii < 16; ++ii) {
        int dl = l32b + 32 * ii;
        unsigned u0 = *(const unsigned*)(yr + 2 * dl + 6);   // y[t-2], y[t-1]
        unsigned u1 = *(const unsigned*)(yr + 2 * dl + 8);   // y[t],   y[t+1]
        unsigned u2 = *(const unsigned*)(yr + 2 * dl + 10);  // y[t+2], y[t+3]
        float v0 = bflo(u0), v1 = bfhi(u0);
        float v2 = bflo(u1), v3 = bfhi(u1);
        float v4 = bflo(u2), v5 = bfhi(u2);
        unsigned t  = 2u * (unsigned)(d0 + dl);
        unsigned r3 = t % 3u;
        float a12 = v1 + v2, a34 = v3 + v4;
        float s0 = v0 + a12, s1 = a12 + v3, s2 = v2 + a34, s3 = a34 + v5;
        float C3a = (r3 == 0u) ? s2 : ((r3 == 1u) ? s1 : s0);
        float C3b = (r3 == 0u) ? s2 : ((r3 == 1u) ? s1 : s3);
        float2 wA = attA[dl];
        float2 wB = attB[dl];
        float  wC = attC[dl];
        float o = wA.x * v2 + wA.y * v3 + wB.x * (v2 + v3) + wB.y * C3a + wC * C3b;
        orow[dl] = o;
    }
}

// ---------------------------------------------------------------------------
extern "C" void kernel_launch(void* const* d_in, const int* in_sizes, int n_in,
                              void* d_out, int out_size, void* d_ws, size_t ws_size,
                              hipStream_t stream) {
    const float* x       = (const float*)d_in[0];
    const float* conv_w  = (const float*)d_in[1];
    const float* conv_b  = (const float*)d_in[2];
    const float* score_w = (const float*)d_in[3];
    float* out = (float*)d_out;

    // workspace (ushort units): Wp[5*512*512] | xT[B*XROWS*E] | yP[B*E*LCP] | zP fp32[B*LCP]
    unsigned short* base = (unsigned short*)d_ws;
    unsigned short* Wp  = base;
    unsigned short* xT  = Wp + (size_t)K_ * E_ * E_;             // 1,310,720
    unsigned short* yP  = xT + (size_t)B_ * XROWS * E_;          // +33,587,200
    float*          zP  = (float*)(yP + (size_t)B_ * E_ * LCP);  // +33,619,968

    wt_kernel<<<dim3((E_ * E_ * K_ + 255) / 256), 256, 0, stream>>>(conv_w, Wp);
    xt_kernel<<<dim3(L_ / 64, E_ / 64, B_), 256, 0, stream>>>(x, xT);
    zero_aux<<<dim3((B_ * LCP + B_ * E_ * 20 + 255) / 256), 256, 0, stream>>>(yP, zP);
    conv_mfma<<<dim3(B_ * 32, E_ / 64), 256, 0, stream>>>(xT, Wp, conv_b, score_w, yP, zP);
    out2_kernel<<<dim3(B_ * 64, LOUT / 512), 256, 0, stream>>>(yP, zP, out);
}

// Round 5
// 411.592 us; speedup vs baseline: 1.2447x; 1.2447x over previous
//
#include <hip/hip_runtime.h>
#include <math.h>

// Problem constants
#define B_    8
#define E_    512
#define L_    8192
#define K_    5
#define LC    8188      // L - K + 1
#define LOUT  4096      // L / DS
#define XROWS 8200      // xT t-rows: 8192 data + 8 slack rows (allocated, only masked outputs read them)
#define LCP   8208      // padded y/z row length: [0,8) front zeros, data at 8+t, back zeros

// Workspace total 137,298,432 B (under round-0 proven 137,592,704 B)

typedef float  f32x4   __attribute__((ext_vector_type(4)));
typedef float  f32x16  __attribute__((ext_vector_type(16)));
typedef short  s16x4   __attribute__((ext_vector_type(4)));
typedef short  s16x8   __attribute__((ext_vector_type(8)));

__device__ __forceinline__ unsigned short f2bf(float f) {
    union { float f; unsigned u; } v; v.f = f;
    unsigned r = v.u + 0x7FFFu + ((v.u >> 16) & 1u);
    return (unsigned short)(r >> 16);
}
__device__ __forceinline__ float bflo(unsigned u) {
    union { unsigned u; float f; } v; v.u = u << 16; return v.f;
}
__device__ __forceinline__ float bfhi(unsigned u) {
    union { unsigned u; float f; } v; v.u = u & 0xFFFF0000u; return v.f;
}

// ---------------------------------------------------------------------------
// Kernel 0: pack conv weight [e][i][k] fp32 -> Wtb[k][e][i] bf16  (round-3)
// ---------------------------------------------------------------------------
__global__ __launch_bounds__(256) void wt_kernel(const float* __restrict__ w,
                                                 unsigned short* __restrict__ Wtb) {
    int idx = blockIdx.x * 256 + threadIdx.x;
    if (idx >= E_ * E_ * K_) return;
    int i    = idx & (E_ - 1);
    int rest = idx >> 9;            // k*E + e
    int e    = rest & (E_ - 1);
    int k    = rest >> 9;
    Wtb[idx] = f2bf(w[((size_t)e * E_ + i) * K_ + k]);
}

// ---------------------------------------------------------------------------
// Kernel 1: transpose x[b][i][t] fp32 -> xT[b][t][i] bf16 (f32x4 loads)
// ---------------------------------------------------------------------------
__global__ __launch_bounds__(256) void xt_kernel(const float* __restrict__ x,
                                                 unsigned short* __restrict__ xT) {
    __shared__ float s[64][65];
    const int b  = blockIdx.z;
    const int i0 = blockIdx.y * 64;
    const int t0 = blockIdx.x * 64;
    #pragma unroll
    for (int j = 0; j < 4; ++j) {
        int idx = threadIdx.x + j * 256;
        int r = idx >> 4, c4 = idx & 15;      // r: i-offset, c4: t-chunk of 4
        f32x4 v = *(const f32x4*)(x + ((size_t)b * E_ + i0 + r) * L_ + t0 + c4 * 4);
        s[c4 * 4 + 0][r] = v[0];
        s[c4 * 4 + 1][r] = v[1];
        s[c4 * 4 + 2][r] = v[2];
        s[c4 * 4 + 3][r] = v[3];
    }
    __syncthreads();
    #pragma unroll
    for (int j = 0; j < 4; ++j) {
        int idx = threadIdx.x + j * 256;
        int tt = idx >> 4, ig = (idx & 15) * 4;
        s16x4 v;
        v[0] = (short)f2bf(s[tt][ig + 0]);
        v[1] = (short)f2bf(s[tt][ig + 1]);
        v[2] = (short)f2bf(s[tt][ig + 2]);
        v[3] = (short)f2bf(s[tt][ig + 3]);
        *(s16x4*)&xT[((size_t)b * XROWS + t0 + tt) * E_ + i0 + ig] = v;
    }
}

// ---------------------------------------------------------------------------
// Kernel 2: zero zP[B][LCP] fully (atomic accumulated) + yP edge pads
// ---------------------------------------------------------------------------
__global__ __launch_bounds__(256) void zero_aux(unsigned short* __restrict__ yP,
                                                float* __restrict__ zP) {
    int idx = blockIdx.x * 256 + threadIdx.x;
    if (idx < B_ * LCP) zP[idx] = 0.f;
    int i2 = idx - B_ * LCP;
    if (i2 >= 0 && i2 < B_ * E_ * 20) {
        int row = i2 / 20, j = i2 - row * 20;
        int col = (j < 8) ? j : (8 + LC + (j - 8));   // front 8 + back 12 pads
        yP[(size_t)row * LCP + col] = 0;
    }
}

// ---------------------------------------------------------------------------
// Kernel 3: implicit-GEMM conv via 32x32x16 bf16 MFMA + fused z-score.
// ROUND-3 VERSION (proven 180 us): block 64e x 512t, 4 waves, wave 64e x 128t.
// ---------------------------------------------------------------------------
__global__ __launch_bounds__(256, 2) void conv_mfma(const unsigned short* __restrict__ xT,
                                                    const unsigned short* __restrict__ Wtb,
                                                    const float* __restrict__ bias,
                                                    const float* __restrict__ sw,
                                                    unsigned short* __restrict__ yP,
                                                    float* __restrict__ zP) {
    __shared__ unsigned short Xs[520][40];   // rows padded to 80 B
    __shared__ unsigned short Ws[K_][64][40];
    __shared__ float swb[128];               // [0:64) = score_w, [64:128) = bias

    const int tid  = threadIdx.x;
    const int nt   = blockIdx.x;
    const int b    = nt >> 4;
    const int tb   = (nt & 15) * 512;
    const int e0   = blockIdx.y * 64;
    const int wave = tid >> 6;
    const int lane = tid & 63;
    const int l32  = lane & 31;
    const int hi   = lane >> 5;
    const int wt0  = wave * 128;

    if (tid < 64)       swb[tid] = sw[e0 + tid];
    else if (tid < 128) swb[tid] = bias[e0 + tid - 64];

    f32x16 acc[2][4];
    #pragma unroll
    for (int es = 0; es < 2; ++es)
        #pragma unroll
        for (int ts = 0; ts < 4; ++ts) acc[es][ts] = (f32x16)0.f;

    const unsigned short* xbase = xT + ((size_t)b * XROWS + tb) * E_;

    s16x8 xpf[9];
    s16x8 wpf[5];

    auto load_tile = [&](int i0) {
        #pragma unroll
        for (int j = 0; j < 8; ++j) {
            int idx = tid + j * 256;
            int r = idx >> 2, c = idx & 3;
            xpf[j] = *(const s16x8*)(xbase + (size_t)r * E_ + i0 + c * 8);
        }
        {
            int idx = tid + 2048;
            if (idx < 2080) {
                int r = idx >> 2, c = idx & 3;
                xpf[8] = *(const s16x8*)(xbase + (size_t)r * E_ + i0 + c * 8);
            }
        }
        #pragma unroll
        for (int j = 0; j < 5; ++j) {
            int idx = tid + j * 256;
            int rl = idx >> 2, c = idx & 3;
            int k = rl >> 6, ep = rl & 63;
            wpf[j] = *(const s16x8*)(Wtb + ((size_t)(k * E_ + e0 + ep) * E_ + i0 + c * 8));
        }
    };
    auto store_tile = [&]() {
        #pragma unroll
        for (int j = 0; j < 8; ++j) {
            int idx = tid + j * 256;
            int r = idx >> 2, c = idx & 3;
            *(s16x8*)&Xs[r][c * 8] = xpf[j];
        }
        {
            int idx = tid + 2048;
            if (idx < 2080) {
                int r = idx >> 2, c = idx & 3;
                *(s16x8*)&Xs[r][c * 8] = xpf[8];
            }
        }
        #pragma unroll
        for (int j = 0; j < 5; ++j) {
            int idx = tid + j * 256;
            int rl = idx >> 2, c = idx & 3;
            int k = rl >> 6, ep = rl & 63;
            *(s16x8*)&Ws[k][ep][c * 8] = wpf[j];
        }
    };

    load_tile(0);
    for (int i0 = 0; i0 < E_; i0 += 32) {
        __syncthreads();            // previous compute done reading LDS
        store_tile();
        __syncthreads();
        if (i0 + 32 < E_) load_tile(i0 + 32);   // latency hidden under MFMAs

        #pragma unroll
        for (int k = 0; k < K_; ++k) {
            #pragma unroll
            for (int kk = 0; kk < 2; ++kk) {
                const int co = kk * 16 + hi * 8;
                s16x8 a0 = *(const s16x8*)&Ws[k][l32][co];
                s16x8 a1 = *(const s16x8*)&Ws[k][32 + l32][co];
                #pragma unroll
                for (int ts = 0; ts < 4; ++ts) {
                    s16x8 bv = *(const s16x8*)&Xs[wt0 + ts * 32 + l32 + k][co];
                    acc[0][ts] = __builtin_amdgcn_mfma_f32_32x32x16_bf16(a0, bv, acc[0][ts], 0, 0, 0);
                    acc[1][ts] = __builtin_amdgcn_mfma_f32_32x32x16_bf16(a1, bv, acc[1][ts], 0, 0, 0);
                }
            }
        }
    }

    // Epilogue: bias add, yP store (bf16, +8 pad offset), fused z partial.
    // C/D layout (32x32): col(t)=lane&31, row(e)=(reg&3)+8*(reg>>2)+4*hi
    #pragma unroll
    for (int ts = 0; ts < 4; ++ts) {
        const int t = tb + wt0 + ts * 32 + l32;
        const bool tv = (t < LC);
        float zp = 0.f;
        #pragma unroll
        for (int es = 0; es < 2; ++es) {
            #pragma unroll
            for (int reg = 0; reg < 16; ++reg) {
                int er = es * 32 + (reg & 3) + 8 * (reg >> 2) + 4 * hi;
                float v = acc[es][ts][reg] + swb[64 + er];
                if (tv) yP[((size_t)(b * E_ + e0 + er)) * LCP + 8 + t] = f2bf(v);
                zp += swb[er] * v;
            }
        }
        zp += __shfl_xor(zp, 32);
        if (hi == 0 && tv) atomicAdd(&zP[(size_t)b * LCP + 8 + t], zp);
    }
}

// ---------------------------------------------------------------------------
// Kernel 4: blend widths 1..3 + 2x downsample.  v3: y read DIRECTLY from
// global (L3-resident, coalesced 4B/lane streams); only z + att in LDS.
// Removes the 130-thread partial y-staging, one barrier, 17 KB LDS.
// Math identical to the verified out2.
// ---------------------------------------------------------------------------
__global__ __launch_bounds__(256) void out3_kernel(const unsigned short* __restrict__ yP,
                                                   const float* __restrict__ zP,
                                                   float* __restrict__ out) {
    __shared__ float  zsL[1040];
    __shared__ float2 attA[512];              // (W1a, W1b)
    __shared__ float2 attB[512];              // (W2, W3a)
    __shared__ float  attC[512];              // W3b
    const int bx  = blockIdx.x;               // b*64 + eg
    const int b   = bx >> 6;
    const int eg  = bx & 63;
    const int d0  = blockIdx.y << 9;          // * 512
    const int tid = threadIdx.x;

    const float* zbase = zP + (size_t)b * LCP + 2 * d0;
    for (int c = tid; c < 260; c += 256)
        *(f32x4*)&zsL[c * 4] = *(const f32x4*)(zbase + c * 4);
    __syncthreads();

    // att weights per d (2 per thread) — window index of t-2 is 2*dl+6
    for (int dl = tid; dl < 512; dl += 256) {
        int lt = 2 * dl + 6;
        float z0 = zsL[lt + 0], z1 = zsL[lt + 1], z2 = zsL[lt + 2];
        float z3 = zsL[lt + 3], z4 = zsL[lt + 4], z5 = zsL[lt + 5];
        unsigned t  = 2u * (unsigned)(d0 + dl);
        unsigned r3 = t % 3u;
        float a12 = z1 + z2, a34 = z3 + z4;
        float s0 = z0 + a12, s1 = a12 + z3, s2 = z2 + a34, s3 = a34 + z5;
        float S1a = z2, S1b = z3;
        float S2  = 0.5f * (z2 + z3);
        float S3a = ((r3 == 0u) ? s2 : ((r3 == 1u) ? s1 : s0)) * (1.f / 3.f);
        float S3b = ((r3 == 0u) ? s2 : ((r3 == 1u) ? s1 : s3)) * (1.f / 3.f);
        float m0 = fmaxf(S1a, fmaxf(S2, S3a));
        float e1 = __expf(S1a - m0), e2 = __expf(S2 - m0), e3 = __expf(S3a - m0);
        float r0 = 1.f / (e1 + e2 + e3);
        float m1 = fmaxf(S1b, fmaxf(S2, S3b));
        float f1 = __expf(S1b - m1), f2 = __expf(S2 - m1), f3 = __expf(S3b - m1);
        float r1 = 1.f / (f1 + f2 + f3);
        attA[dl] = make_float2(0.5f * e1 * r0, 0.5f * f1 * r1);
        attB[dl] = make_float2(0.25f * (e2 * r0 + f2 * r1), (0.5f / 3.f) * e3 * r0);
        attC[dl] = (0.5f / 3.f) * f3 * r1;
    }
    __syncthreads();

    // blend: wave-lane = d (coalesced), 8 e-rows across thread groups.
    // y loaded straight from global: 3 overlapping 4B/lane streams (L1/L3).
    const int e    = tid >> 5;
    const int l32b = tid & 31;
    const unsigned short* yrow = yP + ((size_t)(b * E_ + eg * 8 + e)) * LCP + 2 * d0;
    float* orow = out + ((size_t)(b * E_ + eg * 8 + e)) * LOUT + d0;
    #pragma unroll
    for (int ii = 0; ii < 16; ++ii) {
        int dl = l32b + 32 * ii;
        unsigned u0 = *(const unsigned*)(yrow + 2 * dl + 6);   // y[t-2], y[t-1]
        unsigned u1 = *(const unsigned*)(yrow + 2 * dl + 8);   // y[t],   y[t+1]
        unsigned u2 = *(const unsigned*)(yrow + 2 * dl + 10);  // y[t+2], y[t+3]
        float v0 = bflo(u0), v1 = bfhi(u0);
        float v2 = bflo(u1), v3 = bfhi(u1);
        float v4 = bflo(u2), v5 = bfhi(u2);
        unsigned t  = 2u * (unsigned)(d0 + dl);
        unsigned r3 = t % 3u;
        float a12 = v1 + v2, a34 = v3 + v4;
        float s0 = v0 + a12, s1 = a12 + v3, s2 = v2 + a34, s3 = a34 + v5;
        float C3a = (r3 == 0u) ? s2 : ((r3 == 1u) ? s1 : s0);
        float C3b = (r3 == 0u) ? s2 : ((r3 == 1u) ? s1 : s3);
        float2 wA = attA[dl];
        float2 wB = attB[dl];
        float  wC = attC[dl];
        float o = wA.x * v2 + wA.y * v3 + wB.x * (v2 + v3) + wB.y * C3a + wC * C3b;
        orow[dl] = o;
    }
}

// ---------------------------------------------------------------------------
extern "C" void kernel_launch(void* const* d_in, const int* in_sizes, int n_in,
                              void* d_out, int out_size, void* d_ws, size_t ws_size,
                              hipStream_t stream) {
    const float* x       = (const float*)d_in[0];
    const float* conv_w  = (const float*)d_in[1];
    const float* conv_b  = (const float*)d_in[2];
    const float* score_w = (const float*)d_in[3];
    float* out = (float*)d_out;

    // workspace (ushort units): Wtb[5*512*512] | xT[B*XROWS*E] | yP[B*E*LCP] | zP fp32[B*LCP]
    unsigned short* base = (unsigned short*)d_ws;
    unsigned short* Wtb = base;
    unsigned short* xT  = Wtb + (size_t)K_ * E_ * E_;            // 1,310,720
    unsigned short* yP  = xT + (size_t)B_ * XROWS * E_;          // +33,587,200
    float*          zP  = (float*)(yP + (size_t)B_ * E_ * LCP);  // +33,619,968

    wt_kernel<<<dim3((E_ * E_ * K_ + 255) / 256), 256, 0, stream>>>(conv_w, Wtb);
    xt_kernel<<<dim3(L_ / 64, E_ / 64, B_), 256, 0, stream>>>(x, xT);
    zero_aux<<<dim3((B_ * LCP + B_ * E_ * 20 + 255) / 256), 256, 0, stream>>>(yP, zP);
    conv_mfma<<<dim3(B_ * 16, E_ / 64), 256, 0, stream>>>(xT, Wtb, conv_b, score_w, yP, zP);
    out3_kernel<<<dim3(B_ * 64, LOUT / 512), 256, 0, stream>>>(yP, zP, out);
}